// Round 6
// baseline (202.521 us; speedup 1.0000x reference)
//
#include <hip/hip_runtime.h>
#include <hip/hip_fp16.h>

// EdgeMLP: out[e] = sigmoid( 0.5*dot(relu(af)+relu(ar), W2[:,1]-W2[:,0]) + (b2[1]-b2[0]) )
// Sym/antisym decomposition shares layer-1 work between fwd and rev MLPs:
//   P = 0.5*(W1[0:6]+W1[6:12]), M = 0.5*(W1[0:6]-W1[6:12])
//   cacc = b1 + P^T(xs+xt); macc = M^T(xs-xt)
//   af = cacc+macc+ea*w12, ar = cacc-macc+eaT*w12
//
// R5 post-mortem: drain-all (vmcnt(0)) structure serializes gather latency
// with compute per wave. R6: software-pipelined persistent loop — indices
// 2 iters ahead, gather rows 1 iter ahead, compiler-tracked loads so waits
// are fine-grained vmcnt(N), never a full drain.
//
// d_ws layout:
//   float [0,10)  b1 (cacc init)     float [10] b2d
//   uint  [16,46)  P2[k][j]  (half2 of P[2k][j],P[2k+1][j]),  k<3, j<10
//   uint  [48,78)  M2[k][j]
//   uint  [80,85)  w12_2[jp] (half2 pairs of W1[12][:])
//   uint  [88,93)  w2d_2[jp] (half2 pairs of 0.5*(W2[j][1]-W2[j][0]))
//   byte 4096+:    packed x, 16B/node = 6 fp16 + 2 pad

typedef _Float16 half2_t  __attribute__((ext_vector_type(2)));
typedef _Float16 half8_t  __attribute__((ext_vector_type(8)));
typedef float    float2_v __attribute__((ext_vector_type(2)));
typedef int      int2_v   __attribute__((ext_vector_type(2)));

union h2u { __half2 h; unsigned u; half2_t v; };

__global__ void prep(const float* __restrict__ W1, const float* __restrict__ b1,
                     const float* __restrict__ W2, const float* __restrict__ b2,
                     const float* __restrict__ x, float* __restrict__ wsf, int N) {
    int t = blockIdx.x * 256 + threadIdx.x;
    if (t < N) {   // pack x row t -> 6 fp16 + 2 pad (16B, aligned)
        const float2* xr = (const float2*)x;
        float2 a0 = xr[3 * t], a1 = xr[3 * t + 1], a2 = xr[3 * t + 2];
        union { __half2 h[4]; float4 f; } pk;
        pk.h[0] = __floats2half2_rn(a0.x, a0.y);
        pk.h[1] = __floats2half2_rn(a1.x, a1.y);
        pk.h[2] = __floats2half2_rn(a2.x, a2.y);
        pk.h[3] = __floats2half2_rn(0.0f, 0.0f);
        ((float4*)((char*)wsf + 4096))[t] = pk.f;
    }
    if (blockIdx.x == 0) {
        unsigned* wsu = (unsigned*)wsf;
        int u = threadIdx.x;
        if (u < 10) wsf[u] = b1[u];
        if (u == 0) wsf[10] = b2[1] - b2[0];
        if (u < 30) {                       // P2 / M2: i-pairs (2k, 2k+1)
            int k = u / 10, j = u % 10;
            float a0 = W1[(2 * k) * 10 + j],     c0 = W1[(2 * k + 6) * 10 + j];
            float a1 = W1[(2 * k + 1) * 10 + j], c1 = W1[(2 * k + 7) * 10 + j];
            h2u p, m;
            p.h = __floats2half2_rn(0.5f * (a0 + c0), 0.5f * (a1 + c1));
            m.h = __floats2half2_rn(0.5f * (a0 - c0), 0.5f * (a1 - c1));
            wsu[16 + u] = p.u;
            wsu[48 + u] = m.u;
        }
        if (u < 5) {                        // j-pairs (2u, 2u+1)
            h2u a, b;
            a.h = __floats2half2_rn(W1[120 + 2 * u], W1[120 + 2 * u + 1]);
            b.h = __floats2half2_rn(0.5f * (W2[(2 * u) * 2 + 1] - W2[(2 * u) * 2]),
                                    0.5f * (W2[(2 * u + 1) * 2 + 1] - W2[(2 * u + 1) * 2]));
            wsu[80 + u] = a.u;
            wsu[88 + u] = b.u;
        }
    }
}

static __device__ __forceinline__ float fdot2(half2_t a, half2_t b, float c) {
#if __has_builtin(__builtin_amdgcn_fdot2)
    return __builtin_amdgcn_fdot2(a, b, c, false);
#else
    return fmaf((float)a[0], (float)b[0], fmaf((float)a[1], (float)b[1], c));
#endif
}

static __device__ __forceinline__ half2_t h2bc(const unsigned* wsu, int idx) {
    h2u t; t.u = wsu[idx]; return t.v;
}

// One edge's MLP given packed-half endpoint rows and edge attrs.
static __device__ __forceinline__ float edge_one(half8_t rs, half8_t rt,
                                                 float fea, float feaT,
                                                 const float* __restrict__ wsf,
                                                 const unsigned* __restrict__ wsu) {
    half8_t sv8 = rs + rt;      // v_pk_add_f16 (pad lanes harmless)
    half8_t dv8 = rs - rt;
    half2_t sv[3] = { __builtin_shufflevector(sv8, sv8, 0, 1),
                      __builtin_shufflevector(sv8, sv8, 2, 3),
                      __builtin_shufflevector(sv8, sv8, 4, 5) };
    half2_t dv[3] = { __builtin_shufflevector(dv8, dv8, 0, 1),
                      __builtin_shufflevector(dv8, dv8, 2, 3),
                      __builtin_shufflevector(dv8, dv8, 4, 5) };

    float cacc[10], macc[10];
#pragma unroll
    for (int j = 0; j < 10; ++j) { cacc[j] = wsf[j]; macc[j] = 0.0f; }
#pragma unroll
    for (int k = 0; k < 3; ++k) {
#pragma unroll
        for (int j = 0; j < 10; ++j) {
            cacc[j] = fdot2(sv[k], h2bc(wsu, 16 + k * 10 + j), cacc[j]);
            macc[j] = fdot2(dv[k], h2bc(wsu, 48 + k * 10 + j), macc[j]);
        }
    }

    _Float16 feah  = (_Float16)fea,  feaTh = (_Float16)feaT;
    half2_t fea2  = { feah,  feah  };
    half2_t feaT2 = { feaTh, feaTh };
    half2_t zero2 = { (_Float16)0.0f, (_Float16)0.0f };

    float z = wsf[10];
#pragma unroll
    for (int jp = 0; jp < 5; ++jp) {
        half2_t c2 = { (_Float16)cacc[2 * jp], (_Float16)cacc[2 * jp + 1] };
        half2_t m2 = { (_Float16)macc[2 * jp], (_Float16)macc[2 * jp + 1] };
        half2_t w12 = h2bc(wsu, 80 + jp);
        half2_t af2 = __builtin_elementwise_fma(fea2,  w12, c2 + m2);
        half2_t ar2 = __builtin_elementwise_fma(feaT2, w12, c2 - m2);
        half2_t h2  = __builtin_elementwise_max(af2, zero2) +
                      __builtin_elementwise_max(ar2, zero2);
        z = fdot2(h2, h2bc(wsu, 88 + jp), z);
    }
    return 1.0f / (1.0f + __expf(-z));
}

// Persistent software-pipelined loop. Per iteration: 2 edges. Indices/attrs
// prefetched 2 iterations ahead; gather rows 1 ahead. All loads are
// compiler-tracked -> fine-grained vmcnt(N) waits, no full drain.
__launch_bounds__(256, 4)
__global__ void edge_mlp(const half8_t* __restrict__ xp, const int* __restrict__ ei,
                         const float* __restrict__ ea, const float* __restrict__ eaT,
                         const float* __restrict__ wsf, float* __restrict__ out, int E) {
    const unsigned* wsu = (const unsigned*)wsf;
    const int T = gridDim.x * blockDim.x;
    const int g = blockIdx.x * blockDim.x + threadIdx.x;
    const int npairs = E >> 1;

    if ((E & 1) && g == 0) {          // odd-E epilogue (not hit at E=6.4M)
        int e = E - 1;
        out[e] = edge_one(xp[ei[e]], xp[ei[E + e]], ea[e], eaT[e], wsf, wsu);
    }
    if (npairs == 0) return;

    const int nit = (npairs + T - 1) / T;   // uniform trip count, waves converged
    const int plim = npairs - 1;

    // ---- prologue: stage A (current) and stage B (next) ----
    int pA = min(g, plim);
    int2_v   sA = __builtin_nontemporal_load((const int2_v*)(ei + 2 * pA));
    int2_v   tA = __builtin_nontemporal_load((const int2_v*)(ei + E + 2 * pA));
    float2_v aA = __builtin_nontemporal_load((const float2_v*)(ea + 2 * pA));
    float2_v TA = __builtin_nontemporal_load((const float2_v*)(eaT + 2 * pA));
    int pB = min(g + T, plim);
    int2_v   sB = __builtin_nontemporal_load((const int2_v*)(ei + 2 * pB));
    int2_v   tB = __builtin_nontemporal_load((const int2_v*)(ei + E + 2 * pB));
    float2_v aB = __builtin_nontemporal_load((const float2_v*)(ea + 2 * pB));
    float2_v TB = __builtin_nontemporal_load((const float2_v*)(eaT + 2 * pB));

    half8_t r0A = xp[sA[0]];          // rows for current iteration
    half8_t r1A = xp[tA[0]];
    half8_t r2A = xp[sA[1]];
    half8_t r3A = xp[tA[1]];

    for (int it = 0; it < nit; ++it) {
        // stage 1: issue gathers for it+1 (indices resident since it-1)
        half8_t r0B = xp[sB[0]];
        half8_t r1B = xp[tB[0]];
        half8_t r2B = xp[sB[1]];
        half8_t r3B = xp[tB[1]];

        // stage 2: prefetch indices/attrs for it+2
        int pC = min(g + (it + 2) * T, plim);
        int2_v   sC = __builtin_nontemporal_load((const int2_v*)(ei + 2 * pC));
        int2_v   tC = __builtin_nontemporal_load((const int2_v*)(ei + E + 2 * pC));
        float2_v aC = __builtin_nontemporal_load((const float2_v*)(ea + 2 * pC));
        float2_v TC = __builtin_nontemporal_load((const float2_v*)(eaT + 2 * pC));

        // stage 3: compute current pair (waits only on A-rows: vmcnt(N), N = newer loads)
        float2_v r;
        r[0] = edge_one(r0A, r1A, aA[0], TA[0], wsf, wsu);
        r[1] = edge_one(r2A, r3A, aA[1], TA[1], wsf, wsu);
        int p = g + it * T;
        if (p < npairs)
            __builtin_nontemporal_store(r, (float2_v*)(out + 2 * p));

        // rotate pipeline registers
        sA = sB; tA = tB; aA = aB; TA = TB;
        r0A = r0B; r1A = r1B; r2A = r2B; r3A = r3B;
        sB = sC; tB = tC; aB = aC; TB = TC;
    }
}

extern "C" void kernel_launch(void* const* d_in, const int* in_sizes, int n_in,
                              void* d_out, int out_size, void* d_ws, size_t ws_size,
                              hipStream_t stream) {
    const float* x   = (const float*)d_in[0];
    const int*   ei  = (const int*)d_in[1];
    const float* ea  = (const float*)d_in[2];
    const float* eaT = (const float*)d_in[3];
    const float* W1  = (const float*)d_in[4];
    const float* b1  = (const float*)d_in[5];
    const float* W2  = (const float*)d_in[6];
    const float* b2  = (const float*)d_in[7];
    float* out = (float*)d_out;
    float* ws  = (float*)d_ws;
    int E = in_sizes[2];          // N_EDGES
    int N = in_sizes[0] / 6;      // N_NODES

    int pblocks = (N + 255) / 256;
    prep<<<pblocks, 256, 0, stream>>>(W1, b1, W2, b2, x, ws, N);

    const half8_t* xp = (const half8_t*)((char*)d_ws + 4096);
    edge_mlp<<<1024, 256, 0, stream>>>(xp, ei, ea, eaT, ws, out, E);
}